// Round 4
// baseline (853.448 us; speedup 1.0000x reference)
//
#include <hip/hip_runtime.h>
#include <hip/hip_bf16.h>
#include <stdint.h>

#define NTOK 8192
#define DM   1024
#define DH   2048
#define NE   16

// Per-wave 64x64 register GEMM: 64-thread blocks, no LDS, no barriers.
// 3072 persistent 1-wave workers (12/CU target), per-XCD stealing queues.
#define NWRK  3072
#define QCAP1 8704   // worst case per XCD: 257 m-tiles * 32 panels
#define QCAP2 4352   // 257 * 16

typedef float  f32x4  __attribute__((ext_vector_type(4)));
typedef __bf16 bf16x8 __attribute__((ext_vector_type(8)));

__device__ __forceinline__ unsigned short f2bf(float f) {
  union { __bf16 b; unsigned short u; } c; c.b = (__bf16)f; return c.u;
}

// ---------------- fused prep: router (2048 blocks) + wprep W1 (8192) +
// wprep W2 (8192). All three jobs independent -> one launch, better fill.
__global__ __launch_bounds__(256) void prep_kernel(
    const float* __restrict__ x, const float* __restrict__ Wg,
    unsigned short* __restrict__ xb, int* __restrict__ eidx,
    float* __restrict__ ewt,
    const float* __restrict__ W1, unsigned short* __restrict__ w1t,
    const float* __restrict__ W2, unsigned short* __restrict__ w2t)
{
  __shared__ float t[64][68];
  const int bid = blockIdx.x;

  if (bid < 2048) {
    // ---- router: logits, top-2, softmax; x -> bf16. NO atomics.
    const int lane = threadIdx.x & 63;
    const int wave = threadIdx.x >> 6;
    const int tk = bid * 4 + wave;
    const float* xr = x + (size_t)tk * DM;

    float4 xv[4];
#pragma unroll
    for (int c = 0; c < 4; ++c)
      xv[c] = *(const float4*)(xr + c * 256 + lane * 4);

    unsigned short* xbr = xb + (size_t)tk * DM;
#pragma unroll
    for (int c = 0; c < 4; ++c) {
      ushort4 u;
      u.x = f2bf(xv[c].x); u.y = f2bf(xv[c].y);
      u.z = f2bf(xv[c].z); u.w = f2bf(xv[c].w);
      *(ushort4*)(xbr + c * 256 + lane * 4) = u;
    }

    float acc[NE];
#pragma unroll
    for (int e = 0; e < NE; ++e) acc[e] = 0.f;
#pragma unroll
    for (int e = 0; e < NE; ++e) {
#pragma unroll
      for (int c = 0; c < 4; ++c) {
        float4 wv = *(const float4*)(Wg + e * DM + c * 256 + lane * 4);
        acc[e] += xv[c].x * wv.x + xv[c].y * wv.y + xv[c].z * wv.z + xv[c].w * wv.w;
      }
    }
#pragma unroll
    for (int e = 0; e < NE; ++e) {
      float v = acc[e];
      v += __shfl_xor(v, 1);  v += __shfl_xor(v, 2);  v += __shfl_xor(v, 4);
      v += __shfl_xor(v, 8);  v += __shfl_xor(v, 16); v += __shfl_xor(v, 32);
      acc[e] = v;
    }
    if (lane == 0) {
      float v0 = -1e30f; int i0 = 0;
#pragma unroll
      for (int e = 0; e < NE; ++e) if (acc[e] > v0) { v0 = acc[e]; i0 = e; }
      float v1 = -1e30f; int i1 = 0;
#pragma unroll
      for (int e = 0; e < NE; ++e) if (e != i0 && acc[e] > v1) { v1 = acc[e]; i1 = e; }
      float p = expf(v1 - v0);
      float s = 1.f / (1.f + p);
      eidx[2 * tk] = i0; eidx[2 * tk + 1] = i1;
      ewt[2 * tk] = s;   ewt[2 * tk + 1] = p * s;
    }
    return;
  }

  // ---- weight prep: fp32 [E][K][N] -> bf16 [E][N][K]
  const float* W; unsigned short* WT; int K, N, bx, by, bz;
  if (bid < 2048 + 8192) {
    int i = bid - 2048;
    W = W1; WT = w1t; K = DM; N = DH;
    bx = i & 31; by = (i >> 5) & 15; bz = i >> 9;
  } else {
    int i = bid - 10240;
    W = W2; WT = w2t; K = DH; N = DM;
    bx = i & 15; by = (i >> 4) & 31; bz = i >> 9;
  }
  const int k0 = by * 64;
  const int n0 = bx * 64;
  const int tid = threadIdx.x;
  const int tr = tid >> 2;
  const int tc = (tid & 3) * 16;
  const float* src = W + ((size_t)bz * K + k0) * N + n0;
#pragma unroll
  for (int j = 0; j < 4; ++j) {
    float4 v = *(const float4*)(src + (size_t)tr * N + tc + j * 4);
    t[tc + j * 4 + 0][tr] = v.x;
    t[tc + j * 4 + 1][tr] = v.y;
    t[tc + j * 4 + 2][tr] = v.z;
    t[tc + j * 4 + 3][tr] = v.w;
  }
  __syncthreads();
  unsigned short* dst = WT + ((size_t)bz * N + n0) * K + k0;
#pragma unroll
  for (int j = 0; j < 4; ++j) {
    float4 v = *(const float4*)(&t[tr][tc + j * 4]);
    ushort4 u;
    u.x = f2bf(v.x); u.y = f2bf(v.y); u.z = f2bf(v.z); u.w = f2bf(v.w);
    *(ushort4*)(dst + (size_t)tr * K + tc + j * 4) = u;
  }
}

// ---------------- plan: counts, offsets, scatter, per-XCD contiguous queues -
// XCD x owns experts {x, x+8}. Queue order: expert-outer, panel-outer,
// m-tile-inner (consecutive items share one B panel, L2-hot).
// 64-row tiles: nmt = ceil(cnt/64); GEMM1 panels 32, GEMM2 panels 16.
// Item encoding: (e<<24) | (mt<<12) | p.
__global__ __launch_bounds__(1024) void plan_kernel(
    const int* __restrict__ eidx, const float* __restrict__ ewt,
    int* __restrict__ cnt, int* __restrict__ offv,
    int* __restrict__ tok, float* __restrict__ wtl,
    int* __restrict__ wl1, int* __restrict__ wl2,
    int* __restrict__ qn1, int* __restrict__ qn2,
    int* __restrict__ qc1, int* __restrict__ qc2)
{
  __shared__ int wcnt[16][NE];
  __shared__ int wbase[16][NE];
  __shared__ int offs[NE];
  __shared__ int s_nmt[NE];
  __shared__ int s_pnmt[NE + 1];

  const int tid  = threadIdx.x;
  const int wave = tid >> 6;
  const int lane = tid & 63;
  const unsigned long long below = (1ull << lane) - 1ull;

  // phase 1: cache pairs; per-wave per-expert counts via ballot
  int   pe[16];
  float pw[16];
  int   count[NE];
#pragma unroll
  for (int e = 0; e < NE; ++e) count[e] = 0;
#pragma unroll
  for (int r = 0; r < 16; ++r) {
    int p = wave * 1024 + r * 64 + lane;
    pe[r] = eidx[p];
    pw[r] = ewt[p];
#pragma unroll
    for (int e = 0; e < NE; ++e) {
      unsigned long long m = __ballot(pe[r] == e);
      count[e] += (int)__popcll(m);
    }
  }
  if (lane == 0) {
#pragma unroll
    for (int e = 0; e < NE; ++e) wcnt[wave][e] = count[e];
  }
  __syncthreads();

  // phase 2: thread 0 serial scan; offsets + tile geometry
  if (tid == 0) {
    int s = 0;
    s_pnmt[0] = 0;
    for (int e = 0; e < NE; ++e) {
      offs[e] = s;
      int t = 0;
      for (int w = 0; w < 16; ++w) { wbase[w][e] = t; t += wcnt[w][e]; }
      cnt[e] = t; offv[e] = s; s += t;
      int nmt = (t + 63) >> 6;
      s_nmt[e] = nmt;
      s_pnmt[e + 1] = s_pnmt[e] + nmt;
    }
    offv[NE] = s;
  }
  __syncthreads();

  // queue sizes + counter reset (one thread per XCD)
  if (tid < 8) {
    qn1[tid] = (s_nmt[tid] + s_nmt[tid + 8]) * 32;
    qn2[tid] = (s_nmt[tid] + s_nmt[tid + 8]) * 16;
    qc1[tid] = 0;
    qc2[tid] = 0;
  }

  // phase 2b: parallel dense queue fill (closed-form bijective positions)
  {
    const int totmt = s_pnmt[NE];
    const int T1 = totmt * 32;
    for (int i = tid; i < T1; i += 1024) {
      int gmt = i >> 5, p = i & 31;
      int e = 0;
      while (s_pnmt[e + 1] <= gmt) ++e;
      int mt  = gmt - s_pnmt[e];
      int nmt = s_nmt[e];
      int xx   = e & 7;
      int base = (e < 8) ? 0 : s_nmt[e - 8] * 32;
      wl1[xx * QCAP1 + base + p * nmt + mt] = (e << 24) | (mt << 12) | p;
    }
    const int T2 = totmt * 16;
    for (int i = tid; i < T2; i += 1024) {
      int gmt = i >> 4, p = i & 15;
      int e = 0;
      while (s_pnmt[e + 1] <= gmt) ++e;
      int mt  = gmt - s_pnmt[e];
      int nmt = s_nmt[e];
      int h0  = (nmt + 1) >> 1;   // half-split bounds the hot A slab
      int pos_e = (mt < h0) ? (p * h0 + mt)
                            : (h0 * 16 + p * (nmt - h0) + (mt - h0));
      int xx   = e & 7;
      int base = (e < 8) ? 0 : s_nmt[e - 8] * 16;
      wl2[xx * QCAP2 + base + pos_e] = (e << 24) | (mt << 12) | p;
    }
  }

  // phase 3: rank + scatter tokens (deterministic)
  int run[NE];
#pragma unroll
  for (int e = 0; e < NE; ++e) run[e] = 0;
#pragma unroll
  for (int r = 0; r < 16; ++r) {
    int p = wave * 1024 + r * 64 + lane;
#pragma unroll
    for (int e = 0; e < NE; ++e) {
      unsigned long long m = __ballot(pe[r] == e);
      if (pe[r] == e) {
        int rank = (int)__popcll(m & below);
        int slot = offs[e] + wbase[wave][e] + run[e] + rank;
        tok[slot] = p >> 1;
        wtl[slot] = pw[r];
      }
      run[e] += (int)__popcll(m);
    }
  }
}

// ---------------- per-wave 64x64 register GEMM, no LDS, no barriers --------
// Each 64-thread block is one independent wave computing a 64x64 output tile.
// A/B fragments loaded directly global->VGPR (global_load_dwordx4; lanes with
// equal ln15 coalesce to 64B lines), manually double-buffered at 32-k
// granularity: the compiler's per-register waitcnt pipelines load(h+1) under
// the 16 MFMAs of half-step h. 12 independent waves/CU interleave stalls.
// EPI=0: h = relu(acc+b1) -> bf16    EPI=1: atomicAdd(out, (acc+b2)*w)
template<int GATHER, int EPI, int KDIM, int NDIM, int QCAP>
__global__ __launch_bounds__(64, 3) void gemm_kernel(
    const unsigned short* __restrict__ Abase,
    const unsigned short* __restrict__ BT,
    const float* __restrict__ bias,
    const int* __restrict__ cnt, const int* __restrict__ offv,
    const int* __restrict__ tok, const float* __restrict__ wtl,
    const int* __restrict__ wl, const int* __restrict__ qn,
    int* __restrict__ qc, void* __restrict__ outp)
{
  const int xcd  = blockIdx.x & 7;           // round-robin dispatch -> XCD id
  const int lane = threadIdx.x;
  const int q    = lane >> 4;
  const int ln15 = lane & 15;
  const int myqn = qn[xcd];
  const int* q_  = wl + xcd * QCAP;
  constexpr int KH = KDIM / 32;              // 32-k half-steps

  for (;;) {
    int j = 0;
    if (lane == 0) j = atomicAdd(&qc[xcd], 1);
    j = __shfl(j, 0);
    if (j >= myqn) return;                   // wave-uniform exit
    const int v = q_[j];

    const int e  = v >> 24;
    const int m0 = ((v >> 12) & 0xfff) * 64;
    const int n0 = (v & 0xfff) * 64;
    const int count = cnt[e];
    const int o     = offv[e];

    // fragment row pointers: lane (q, ln15) reads k-chunk q*8..q*8+7 of its
    // rows; rows a*16+ln15 (A) / cols a*16+ln15 (B, pre-transposed [N][K]).
    const unsigned short* ap[4];
    const unsigned short* bp[4];
#pragma unroll
    for (int a = 0; a < 4; ++a) {
      int m = m0 + a * 16 + ln15; if (m > count - 1) m = count - 1;
      size_t arow = GATHER ? (size_t)tok[o + m] : (size_t)(o + m);
      ap[a] = Abase + arow * KDIM + q * 8;
      bp[a] = BT + ((size_t)e * NDIM + n0 + a * 16 + ln15) * KDIM + q * 8;
    }

    f32x4 acc[4][4];
#pragma unroll
    for (int a = 0; a < 4; ++a)
#pragma unroll
      for (int b = 0; b < 4; ++b) acc[a][b] = 0.f;

    bf16x8 a0[4], b0[4], a1[4], b1[4];

#define LOADH(A_, B_, H_) {                                               \
    _Pragma("unroll")                                                     \
    for (int a = 0; a < 4; ++a) {                                         \
      A_[a] = *(const bf16x8*)(ap[a] + (H_) * 32);                        \
      B_[a] = *(const bf16x8*)(bp[a] + (H_) * 32);                        \
    } }
#define MFMAH(A_, B_) {                                                   \
    _Pragma("unroll")                                                     \
    for (int a = 0; a < 4; ++a)                                           \
      _Pragma("unroll")                                                   \
      for (int b = 0; b < 4; ++b)                                         \
        acc[a][b] = __builtin_amdgcn_mfma_f32_16x16x32_bf16(              \
            A_[a], B_[b], acc[a][b], 0, 0, 0);                            \
    }

    LOADH(a0, b0, 0)
    for (int kh = 0; kh < KH - 2; kh += 2) {
      LOADH(a1, b1, kh + 1)
      MFMAH(a0, b0)
      LOADH(a0, b0, kh + 2)
      MFMAH(a1, b1)
    }
    LOADH(a1, b1, KH - 1)
    MFMAH(a0, b0)
    MFMAH(a1, b1)
#undef LOADH
#undef MFMAH

    float bn[4];
#pragma unroll
    for (int b = 0; b < 4; ++b)
      bn[b] = bias[(size_t)e * NDIM + n0 + b * 16 + ln15];

    // C layout: row = a*16 + q*4 + rg, col = b*16 + ln15
    if (EPI == 0) {
      unsigned short* hout = (unsigned short*)outp;
#pragma unroll
      for (int a = 0; a < 4; ++a)
#pragma unroll
        for (int rg = 0; rg < 4; ++rg) {
          int m = m0 + a * 16 + q * 4 + rg;
          if (m < count) {
            size_t slot = (size_t)(o + m);
#pragma unroll
            for (int b = 0; b < 4; ++b) {
              float v2 = acc[a][b][rg] + bn[b];
              v2 = v2 > 0.f ? v2 : 0.f;
              hout[slot * NDIM + n0 + b * 16 + ln15] = f2bf(v2);
            }
          }
        }
    } else {
      float* obase = (float*)outp;
#pragma unroll
      for (int a = 0; a < 4; ++a)
#pragma unroll
        for (int rg = 0; rg < 4; ++rg) {
          int m = m0 + a * 16 + q * 4 + rg;
          if (m < count) {
            int slot = o + m;
            int tk = tok[slot];
            float w = wtl[slot];
#pragma unroll
            for (int b = 0; b < 4; ++b) {
              float v2 = (acc[a][b][rg] + bn[b]) * w;
              atomicAdd(&obase[(size_t)tk * NDIM + n0 + b * 16 + ln15], v2);
            }
          }
        }
    }
  }
}

// ---------------- launch ----------------------------------------------------
extern "C" void kernel_launch(void* const* d_in, const int* in_sizes, int n_in,
                              void* d_out, int out_size, void* d_ws, size_t ws_size,
                              hipStream_t stream) {
  const float* x  = (const float*)d_in[0];
  const float* Wg = (const float*)d_in[1];
  const float* W1 = (const float*)d_in[2];
  const float* b1 = (const float*)d_in[3];
  const float* W2 = (const float*)d_in[4];
  const float* b2 = (const float*)d_in[5];

  constexpr size_t OFF_CNT  = 0;
  constexpr size_t OFF_OFF  = 256;
  constexpr size_t OFF_QN1  = 512;
  constexpr size_t OFF_QN2  = 544;
  constexpr size_t OFF_QC1  = 576;
  constexpr size_t OFF_QC2  = 608;
  constexpr size_t OFF_WL1  = 8192;
  constexpr size_t OFF_WL2  = OFF_WL1 + (size_t)8 * QCAP1 * 4;   // 278528 B
  constexpr size_t OFF_EIDX = OFF_WL2 + (size_t)8 * QCAP2 * 4;   // 139264 B
  constexpr size_t OFF_EWT  = OFF_EIDX + (size_t)NTOK * 2 * 4;
  constexpr size_t OFF_TOK  = OFF_EWT  + (size_t)NTOK * 2 * 4;
  constexpr size_t OFF_WTL  = OFF_TOK  + (size_t)NTOK * 2 * 4;
  constexpr size_t OFF_XB   = (size_t)1 << 20;
  constexpr size_t OFF_W1T  = OFF_XB  + (size_t)NTOK * DM * 2;
  constexpr size_t OFF_W2T  = OFF_W1T + (size_t)NE * DM * DH * 2;
  constexpr size_t OFF_H    = OFF_W2T + (size_t)NE * DH * DM * 2;
  constexpr size_t REQ      = OFF_H   + (size_t)NTOK * 2 * DH * 2;
  static_assert(OFF_WTL + (size_t)NTOK * 2 * 4 <= OFF_XB, "ws layout overlap");

  if (ws_size < REQ) {
    hipMemsetAsync(d_out, 0, (size_t)out_size * 4, stream);
    return;
  }

  char* ws = (char*)d_ws;
  int*   cnt    = (int*)(ws + OFF_CNT);
  int*   offv   = (int*)(ws + OFF_OFF);
  int*   qn1    = (int*)(ws + OFF_QN1);
  int*   qn2    = (int*)(ws + OFF_QN2);
  int*   qc1    = (int*)(ws + OFF_QC1);
  int*   qc2    = (int*)(ws + OFF_QC2);
  int*   wl1    = (int*)(ws + OFF_WL1);
  int*   wl2    = (int*)(ws + OFF_WL2);
  int*   eidx   = (int*)(ws + OFF_EIDX);
  float* ewt    = (float*)(ws + OFF_EWT);
  int*   tok    = (int*)(ws + OFF_TOK);
  float* wtl    = (float*)(ws + OFF_WTL);
  unsigned short* xb   = (unsigned short*)(ws + OFF_XB);
  unsigned short* w1t  = (unsigned short*)(ws + OFF_W1T);
  unsigned short* w2t  = (unsigned short*)(ws + OFF_W2T);
  unsigned short* hbuf = (unsigned short*)(ws + OFF_H);

  hipMemsetAsync(d_out, 0, (size_t)out_size * 4, stream);   // atomic target

  // router (2048) + wprep W1 (8192) + wprep W2 (8192) fused: one launch
  prep_kernel<<<18432, 256, 0, stream>>>(x, Wg, xb, eidx, ewt, W1, w1t, W2, w2t);
  plan_kernel<<<1, 1024, 0, stream>>>(eidx, ewt, cnt, offv, tok, wtl,
                                      wl1, wl2, qn1, qn2, qc1, qc2);

  // GEMM1: h = relu(x @ W1 + b1), gathered rows, K=1024, N=2048
  gemm_kernel<1, 0, DM, DH, QCAP1><<<NWRK, 64, 0, stream>>>(
      xb, w1t, b1, cnt, offv, tok, wtl, wl1, qn1, qc1, hbuf);
  // GEMM2: out[tok] += (h @ W2 + b2) * w, K=2048, N=1024
  gemm_kernel<0, 1, DH, DM, QCAP2><<<NWRK, 64, 0, stream>>>(
      hbuf, w2t, b2, cnt, offv, tok, wtl, wl2, qn2, qc2, (float*)d_out);
}